// Round 1
// 130.882 us; speedup vs baseline: 1.0086x; 1.0086x over previous
//
#include <hip/hip_runtime.h>
#include <math.h>

typedef _Float16 f16;
typedef _Float16 half4_t __attribute__((ext_vector_type(4)));
typedef _Float16 half8_t __attribute__((ext_vector_type(8)));
typedef float floatx4 __attribute__((ext_vector_type(4)));

// ------------------------------------------------------------------
// Kernel P: repack weights fp32 -> f16, transposed [col][k] so B-operand
// fragments (k-chunks of 8) are contiguous 16B loads.
// ------------------------------------------------------------------
__global__ __launch_bounds__(256) void prep_weights(
    const float* __restrict__ W1, const float* __restrict__ W2,
    const float* __restrict__ W3, f16* __restrict__ wt) {
  int t = blockIdx.x * 256 + threadIdx.x;
  if (t < 8192) {                       // W1t [128][64]
    int c = t >> 6, k = t & 63;
    wt[t] = (f16)W1[k * 128 + c];
  } else if (t < 24576) {               // W2t [128][128]
    int u = t - 8192;
    int c = u >> 7, k = u & 127;
    wt[t] = (f16)W2[k * 128 + c];
  } else if (t < 43008) {               // W3t [144][128], cols 136..143 zero
    int u = t - 24576;
    int c = u >> 7, k = u & 127;
    wt[t] = (f16)((c < 136) ? W3[k * 136 + c] : 0.0f);
  }
}

// fast tanh: tanh(x) = 1 - 2/(e^{2x}+1)
__device__ __forceinline__ float fast_tanh(float v) {
  float e = __builtin_amdgcn_exp2f(v * 2.885390081777926814f);  // 2*log2(e)
  return 1.0f - 2.0f * __builtin_amdgcn_rcpf(e + 1.0f);
}

// ---- DPP wave64 sum: row_shr 1/2/4/8 then row_bcast 15/31; total in lane 63.
template <int CTRL>
__device__ __forceinline__ float dpp_add(float v) {
  int t = __builtin_amdgcn_update_dpp(0, __builtin_bit_cast(int, v), CTRL,
                                      0xf, 0xf, true);
  return v + __builtin_bit_cast(float, t);
}
__device__ __forceinline__ float wsum(float v) {
  v = dpp_add<0x111>(v);  // row_shr:1
  v = dpp_add<0x112>(v);  // row_shr:2
  v = dpp_add<0x114>(v);  // row_shr:4
  v = dpp_add<0x118>(v);  // row_shr:8
  v = dpp_add<0x142>(v);  // row_bcast:15
  v = dpp_add<0x143>(v);  // row_bcast:31
  return __builtin_bit_cast(
      float, __builtin_amdgcn_readlane(__builtin_bit_cast(int, v), 63));
}

// round floatx4 -> half4 via packed RTZ converts
__device__ __forceinline__ half4_t to_h(floatx4 v) {
  auto p0 = __builtin_amdgcn_cvt_pkrtz(v[0], v[1]);
  auto p1 = __builtin_amdgcn_cvt_pkrtz(v[2], v[3]);
  half4_t h;
  h[0] = p0[0]; h[1] = p0[1]; h[2] = p1[0]; h[3] = p1[1];
  return h;
}

// ------------------------------------------------------------------
// p = expm(B - m I), m = trace/16. Canonical symmetric fragment layout:
// lane value_i = X[l&15][4*(l>>4)+i] is simultaneously a valid A, B and C/D
// layout for v_mfma_f32_16x16x16_f16 (polynomials of a symmetric matrix stay
// symmetric -> zero cross-lane data movement). Degree-4 Paterson-Stockmeyer,
// spectral bound theta <= 0.354 via Frobenius power-of-2 scaling.
// ------------------------------------------------------------------
__device__ __forceinline__ floatx4 expm_c(floatx4 b, floatx4 I4, float& m) {
  float s2 = wsum(b[0] * b[0] + b[1] * b[1] + b[2] * b[2] + b[3] * b[3]);
  float td = wsum(I4[0] * b[0] + I4[1] * b[1] + I4[2] * b[2] + I4[3] * b[3]);
  m = td * 0.0625f;
  float fr2 = fmaxf(s2 - td * m, 1e-30f);  // ||B - mI||_F^2
  int e2 = (int)(__builtin_bit_cast(unsigned, fr2) >> 23) - 127;
  int s = (e2 + 5) >> 1;  // guarantees 2^-s * fr <= 2^-1.5 = 0.354
  s = s < 0 ? 0 : (s > 12 ? 12 : s);
  s = __builtin_amdgcn_readfirstlane(s);
  float sc = __builtin_bit_cast(float, (unsigned)(127 - s) << 23);  // 2^-s
  b = (b - I4 * m) * sc;
  half4_t bh = to_h(b);
  floatx4 zero = {0.f, 0.f, 0.f, 0.f};
  floatx4 a2 = __builtin_amdgcn_mfma_f32_16x16x16f16(bh, bh, zero, 0, 0, 0);
  // deg-4 Taylor: I + b + a2*(I/2 + b/6 + a2/24)
  floatx4 t = I4 * 0.5f + b * (1.f / 6.f) + a2 * (1.f / 24.f);
  floatx4 p = __builtin_amdgcn_mfma_f32_16x16x16f16(to_h(a2), to_h(t), I4 + b,
                                                    0, 0, 0);
  for (int k = 0; k < s; ++k) {
    half4_t ph = to_h(p);
    p = __builtin_amdgcn_mfma_f32_16x16x16f16(ph, ph, zero, 0, 0, 0);
  }
  return p;
}

// ------------------------------------------------------------------
// Fused kernel: MLP (column-split across 4 waves, weights in VGPRs) +
// expm chain, ldata never leaves LDS.
//   block = 256 threads (4 waves), 32 batch rows (2 row-tiles of 16).
//   Wave w owns output-column groups c8g = w + 4*j:
//     L1/L2: j in {0,1}  (8 groups of 16 cols)  -> 16/64 VGPR of frags
//     L3   : j in {0,1,2}, guarded c8g < 9      -> 48 VGPR of frags
//   Activations pass through barrier-synced LDS (act1 -> act2), XOR-swizzled
//   8-f16 groups: conflict-free ds_read_b128 A-fragments.
//   Then each wave runs the eigh-free expm identity
//     out = normalize_F( expm( expm(2Q)/2 ) )
//   for 8 of the block's 32 matrices, reading ldata from LDS.
// ------------------------------------------------------------------
__global__ __launch_bounds__(256, 2) void fused_kernel(
    const float* __restrict__ x, const float* __restrict__ b1,
    const float* __restrict__ b2v, const float* __restrict__ b3,
    const f16* __restrict__ wt, float* __restrict__ out) {
  __shared__ f16 act1[2048];        // 16 rows x 128 cols (h1)
  __shared__ f16 act2[2048];        // 16 rows x 128 cols (h2)
  __shared__ f16 lds_ld[32 * 144];  // 32 rows x 144 chol cols (136 real)

  const int lane = threadIdx.x & 63;
  const int w = threadIdx.x >> 6;  // wave 0..3
  const int cl = lane & 15;        // A-row / C-col index
  const int q = lane >> 4;         // quad: k-chunk / C-row-group
  const f16* w1t = wt;             // [128][64]
  const f16* w2t = wt + 8192;      // [128][128]
  const f16* w3t = wt + 24576;     // [144][128]

  // ---- one-time: this wave's quarter of W1/W2/W3 fragments + biases ----
  half8_t w1f[2][2], w2f[2][4], w3f[3][4];
  float bias1[2], bias2[2], bias3[3];
#pragma unroll
  for (int j = 0; j < 2; ++j) {
    int c8g = w + 4 * j;
    int c = c8g * 16 + cl;
#pragma unroll
    for (int ks = 0; ks < 2; ++ks)
      w1f[j][ks] = *(const half8_t*)(w1t + c * 64 + ks * 32 + q * 8);
#pragma unroll
    for (int ks = 0; ks < 4; ++ks)
      w2f[j][ks] = *(const half8_t*)(w2t + c * 128 + ks * 32 + q * 8);
    bias1[j] = b1[c];
    bias2[j] = b2v[c];
  }
#pragma unroll
  for (int j = 0; j < 3; ++j) {
    int c8g = w + 4 * j;
    int c8c = c8g < 9 ? c8g : 8;  // clamp so loads stay in-bounds (unused)
    int c = c8c * 16 + cl;
#pragma unroll
    for (int ks = 0; ks < 4; ++ks)
      w3f[j][ks] = *(const half8_t*)(w3t + c * 128 + ks * 32 + q * 8);
    int cc = c8g * 16 + cl;
    bias3[j] = (cc < 136) ? b3[cc] : 0.f;
  }

  const int r0b = blockIdx.x * 32;
  // prefetch row-tile 0's x rows (all 4 waves load same addrs: L1-hit)
  const float* xp = x + (size_t)(r0b + cl) * 64 + q * 8;
  floatx4 v0 = *(const floatx4*)xp;
  floatx4 v1 = *(const floatx4*)(xp + 4);
  floatx4 v2 = *(const floatx4*)(xp + 32);
  floatx4 v3 = *(const floatx4*)(xp + 36);

  for (int t = 0; t < 2; ++t) {
    half8_t a0, a1;
#pragma unroll
    for (int i = 0; i < 4; ++i) {
      a0[i] = (f16)v0[i]; a0[i + 4] = (f16)v1[i];
      a1[i] = (f16)v2[i]; a1[i + 4] = (f16)v3[i];
    }
    if (t == 0) {  // prefetch tile 1's x rows
      xp = x + (size_t)(r0b + 16 + cl) * 64 + q * 8;
      v0 = *(const floatx4*)xp;
      v1 = *(const floatx4*)(xp + 4);
      v2 = *(const floatx4*)(xp + 32);
      v3 = *(const floatx4*)(xp + 36);
    }

    // ---- Layer 1: [16x64] @ [64x128], this wave's 2 col-groups ----
#pragma unroll
    for (int j = 0; j < 2; ++j) {
      int c8g = w + 4 * j;
      floatx4 acc = {0.f, 0.f, 0.f, 0.f};
      acc = __builtin_amdgcn_mfma_f32_16x16x32_f16(a0, w1f[j][0], acc, 0, 0, 0);
      acc = __builtin_amdgcn_mfma_f32_16x16x32_f16(a1, w1f[j][1], acc, 0, 0, 0);
#pragma unroll
      for (int i = 0; i < 4; ++i) {
        float v = acc[i] + bias1[j];
        v = v > 0.f ? v : 0.01f * v;  // LeakyReLU
        int row = q * 4 + i;
        int gs = ((c8g * 2 + (cl >> 3)) ^ row) & 15;  // XOR-swizzled group
        act1[row * 128 + gs * 8 + (cl & 7)] = (f16)v;
      }
    }
    __syncthreads();

    half8_t ha[4];
#pragma unroll
    for (int ks = 0; ks < 4; ++ks)
      ha[ks] = *(const half8_t*)(act1 + cl * 128 +
                                 ((((ks << 2) | q) ^ cl) << 3));

    // ---- Layer 2: [16x128] @ [128x128] ----
#pragma unroll
    for (int j = 0; j < 2; ++j) {
      int c8g = w + 4 * j;
      floatx4 acc = {0.f, 0.f, 0.f, 0.f};
#pragma unroll
      for (int ks = 0; ks < 4; ++ks)
        acc = __builtin_amdgcn_mfma_f32_16x16x32_f16(ha[ks], w2f[j][ks], acc,
                                                     0, 0, 0);
#pragma unroll
      for (int i = 0; i < 4; ++i) {
        float v = acc[i] + bias2[j];
        v = v > 0.f ? v : 0.01f * v;
        int row = q * 4 + i;
        int gs = ((c8g * 2 + (cl >> 3)) ^ row) & 15;
        act2[row * 128 + gs * 8 + (cl & 7)] = (f16)v;
      }
    }
    __syncthreads();

#pragma unroll
    for (int ks = 0; ks < 4; ++ks)
      ha[ks] = *(const half8_t*)(act2 + cl * 128 +
                                 ((((ks << 2) | q) ^ cl) << 3));

    // ---- Layer 3: [16x128] @ [128x136] + tanh -> ldata in LDS ----
#pragma unroll
    for (int j = 0; j < 3; ++j) {
      int c8g = w + 4 * j;
      if (c8g < 9) {
        floatx4 acc = {0.f, 0.f, 0.f, 0.f};
#pragma unroll
        for (int ks = 0; ks < 4; ++ks)
          acc = __builtin_amdgcn_mfma_f32_16x16x32_f16(ha[ks], w3f[j][ks], acc,
                                                       0, 0, 0);
        int c = c8g * 16 + cl;  // 0..143; cols >=136 are zero-weight scratch
#pragma unroll
        for (int i = 0; i < 4; ++i) {
          float v = fast_tanh(acc[i] + bias3[j]);
          lds_ld[(t * 16 + q * 4 + i) * 144 + c] = (f16)v;
        }
      }
    }
    // no barrier here: next tile touches act1 only after its own post-L1
    // barrier, and all act1/act2 reads for this tile already happened.
  }
  __syncthreads();  // ldata complete in LDS

  // ---- expm phase: 8 matrices per wave, ldata read from LDS ----
  const int r = cl;
#pragma unroll 2
  for (int jj = 0; jj < 8; ++jj) {
    int m_loc = w * 8 + jj;
    const f16* ld = lds_ld + m_loc * 144;

    floatx4 b, I4;
#pragma unroll
    for (int i = 0; i < 4; ++i) {
      int k = q * 4 + i;
      int hi = r > k ? r : k;
      int lo = r + k - hi;
      float v = (float)ld[hi * (hi + 1) / 2 + lo];  // tril row-major index
      bool d = (r == k);
      I4[i] = d ? 1.f : 0.f;
      b[i] = d ? 4.f * v : 2.f * v;  // b = 2*Q (Q diag = 2*ldata)
    }

    // expm #1: p = expm(2Q - m1 I);  Z/2 = e^{m1}/2 * p (exact algebra)
    float m1;
    floatx4 p = expm_c(b, I4, m1);
    float fac = __builtin_amdgcn_exp2f(m1 * 1.4426950408889634f - 1.0f);
    // expm #2: shift constant cancels in the final Frobenius normalization
    float m2;
    p = expm_c(p * fac, I4, m2);

    float n2 = wsum(p[0] * p[0] + p[1] * p[1] + p[2] * p[2] + p[3] * p[3]);
    float inv = __builtin_amdgcn_rsqf(n2);
    floatx4 o = p * inv;
    size_t mat = (size_t)(r0b + m_loc);
    // value_i = M[r][4q+i] -> out[mat*256 + r*16 + 4q + i]
    *(floatx4*)(out + mat * 256 + r * 16 + q * 4) = o;
  }
}

// ------------------------------------------------------------------
extern "C" void kernel_launch(void* const* d_in, const int* in_sizes, int n_in,
                              void* d_out, int out_size, void* d_ws,
                              size_t ws_size, hipStream_t stream) {
  const float* x = (const float*)d_in[0];
  const float* W1 = (const float*)d_in[1];
  const float* b1 = (const float*)d_in[2];
  const float* W2 = (const float*)d_in[3];
  const float* b2 = (const float*)d_in[4];
  const float* W3 = (const float*)d_in[5];
  const float* b3 = (const float*)d_in[6];
  float* out = (float*)d_out;
  f16* wt = (f16*)d_ws;

  prep_weights<<<168, 256, 0, stream>>>(W1, W2, W3, wt);
  fused_kernel<<<2048, 256, 0, stream>>>(x, b1, b2, b3, wt, out);
}

// Round 2
// 127.719 us; speedup vs baseline: 1.0335x; 1.0248x over previous
//
#include <hip/hip_runtime.h>
#include <math.h>

typedef _Float16 f16;
typedef _Float16 half4_t __attribute__((ext_vector_type(4)));
typedef _Float16 half8_t __attribute__((ext_vector_type(8)));
typedef float floatx4 __attribute__((ext_vector_type(4)));

// ------------------------------------------------------------------
// Kernel P: repack weights fp32 -> f16, transposed [col][k] so B-operand
// fragments (k-chunks of 8) are contiguous 16B loads.
// ------------------------------------------------------------------
__global__ __launch_bounds__(256) void prep_weights(
    const float* __restrict__ W1, const float* __restrict__ W2,
    const float* __restrict__ W3, f16* __restrict__ wt) {
  int t = blockIdx.x * 256 + threadIdx.x;
  if (t < 8192) {                       // W1t [128][64]
    int c = t >> 6, k = t & 63;
    wt[t] = (f16)W1[k * 128 + c];
  } else if (t < 24576) {               // W2t [128][128]
    int u = t - 8192;
    int c = u >> 7, k = u & 127;
    wt[t] = (f16)W2[k * 128 + c];
  } else if (t < 43008) {               // W3t [144][128], cols 136..143 zero
    int u = t - 24576;
    int c = u >> 7, k = u & 127;
    wt[t] = (f16)((c < 136) ? W3[k * 136 + c] : 0.0f);
  }
}

// fast tanh: tanh(x) = 1 - 2/(e^{2x}+1)
__device__ __forceinline__ float fast_tanh(float v) {
  float e = __builtin_amdgcn_exp2f(v * 2.885390081777926814f);  // 2*log2(e)
  return 1.0f - 2.0f * __builtin_amdgcn_rcpf(e + 1.0f);
}

// ---- DPP wave64 sum: row_shr 1/2/4/8 then row_bcast 15/31; total in lane 63.
template <int CTRL>
__device__ __forceinline__ float dpp_add(float v) {
  int t = __builtin_amdgcn_update_dpp(0, __builtin_bit_cast(int, v), CTRL,
                                      0xf, 0xf, true);
  return v + __builtin_bit_cast(float, t);
}
__device__ __forceinline__ float wsum(float v) {
  v = dpp_add<0x111>(v);  // row_shr:1
  v = dpp_add<0x112>(v);  // row_shr:2
  v = dpp_add<0x114>(v);  // row_shr:4
  v = dpp_add<0x118>(v);  // row_shr:8
  v = dpp_add<0x142>(v);  // row_bcast:15
  v = dpp_add<0x143>(v);  // row_bcast:31
  return __builtin_bit_cast(
      float, __builtin_amdgcn_readlane(__builtin_bit_cast(int, v), 63));
}

// round floatx4 -> half4 via packed RTZ converts
__device__ __forceinline__ half4_t to_h(floatx4 v) {
  auto p0 = __builtin_amdgcn_cvt_pkrtz(v[0], v[1]);
  auto p1 = __builtin_amdgcn_cvt_pkrtz(v[2], v[3]);
  half4_t h;
  h[0] = p0[0]; h[1] = p0[1]; h[2] = p1[0]; h[3] = p1[1];
  return h;
}

__device__ __forceinline__ float dot4(floatx4 a, floatx4 b) {
  return a[0] * b[0] + a[1] * b[1] + a[2] * b[2] + a[3] * b[3];
}

// ------------------------------------------------------------------
// PAIRED p = expm(B - m I) for two independent matrices A,B.
// Same math as the single version (canonical symmetric fragment layout,
// deg-4 Paterson-Stockmeyer, Frobenius power-of-2 scaling), but the two
// squaring chains share one loop of max(sA,sB) iterations with wave-uniform
// predicated updates -> 2x ILP on the dominant to_h->MFMA latency chain.
// Bit-identical per matrix (discarded MFMAs only).
// ------------------------------------------------------------------
__device__ __forceinline__ void expm_c2(floatx4& pA_, floatx4& pB_,
                                        floatx4 bA, floatx4 bB, floatx4 I4,
                                        float& mA_, float& mB_) {
  float s2A = wsum(dot4(bA, bA));
  float s2B = wsum(dot4(bB, bB));
  float tdA = wsum(dot4(I4, bA));
  float tdB = wsum(dot4(I4, bB));
  float mA = tdA * 0.0625f, mB = tdB * 0.0625f;
  float frA = fmaxf(s2A - tdA * mA, 1e-30f);  // ||B - mI||_F^2
  float frB = fmaxf(s2B - tdB * mB, 1e-30f);
  int eA = (int)(__builtin_bit_cast(unsigned, frA) >> 23) - 127;
  int eB = (int)(__builtin_bit_cast(unsigned, frB) >> 23) - 127;
  int sA = (eA + 5) >> 1;  // guarantees 2^-s * fr <= 2^-1.5 = 0.354
  int sB = (eB + 5) >> 1;
  sA = sA < 0 ? 0 : (sA > 12 ? 12 : sA);
  sB = sB < 0 ? 0 : (sB > 12 ? 12 : sB);
  sA = __builtin_amdgcn_readfirstlane(sA);
  sB = __builtin_amdgcn_readfirstlane(sB);
  float scA = __builtin_bit_cast(float, (unsigned)(127 - sA) << 23);  // 2^-s
  float scB = __builtin_bit_cast(float, (unsigned)(127 - sB) << 23);
  bA = (bA - I4 * mA) * scA;
  bB = (bB - I4 * mB) * scB;
  half4_t bhA = to_h(bA), bhB = to_h(bB);
  floatx4 zero = {0.f, 0.f, 0.f, 0.f};
  floatx4 a2A = __builtin_amdgcn_mfma_f32_16x16x16f16(bhA, bhA, zero, 0, 0, 0);
  floatx4 a2B = __builtin_amdgcn_mfma_f32_16x16x16f16(bhB, bhB, zero, 0, 0, 0);
  // deg-4 Taylor: I + b + a2*(I/2 + b/6 + a2/24)
  floatx4 tA = I4 * 0.5f + bA * (1.f / 6.f) + a2A * (1.f / 24.f);
  floatx4 tB = I4 * 0.5f + bB * (1.f / 6.f) + a2B * (1.f / 24.f);
  floatx4 pA = __builtin_amdgcn_mfma_f32_16x16x16f16(to_h(a2A), to_h(tA),
                                                     I4 + bA, 0, 0, 0);
  floatx4 pB = __builtin_amdgcn_mfma_f32_16x16x16f16(to_h(a2B), to_h(tB),
                                                     I4 + bB, 0, 0, 0);
  int smax = sA > sB ? sA : sB;
  for (int k = 0; k < smax; ++k) {
    half4_t phA = to_h(pA), phB = to_h(pB);
    floatx4 qA = __builtin_amdgcn_mfma_f32_16x16x16f16(phA, phA, zero, 0, 0, 0);
    floatx4 qB = __builtin_amdgcn_mfma_f32_16x16x16f16(phB, phB, zero, 0, 0, 0);
    pA = (k < sA) ? qA : pA;  // wave-uniform predication: bit-identical
    pB = (k < sB) ? qB : pB;
  }
  pA_ = pA;
  pB_ = pB;
  mA_ = mA;
  mB_ = mB;
}

// ------------------------------------------------------------------
// Fused kernel: MLP (column-split across 4 waves, weights in VGPRs) +
// paired expm chains, ldata never leaves LDS.
//   block = 256 threads (4 waves), 32 batch rows (2 row-tiles of 16).
//   Wave w owns output-column groups c8g = w + 4*j:
//     L1/L2: j in {0,1}  (8 groups of 16 cols)
//     L3   : j in {0,1,2}, guarded c8g < 9
//   Activations pass through barrier-synced LDS (act1 -> act2), XOR-swizzled
//   8-f16 groups: conflict-free ds_read_b128 A-fragments.
//   Then each wave runs the eigh-free expm identity
//     out = normalize_F( expm( expm(2Q)/2 ) )
//   for 8 of the block's 32 matrices (4 interleaved PAIRS), ldata from LDS.
// ------------------------------------------------------------------
__global__ __launch_bounds__(256, 2) void fused_kernel(
    const float* __restrict__ x, const float* __restrict__ b1,
    const float* __restrict__ b2v, const float* __restrict__ b3,
    const f16* __restrict__ wt, float* __restrict__ out) {
  __shared__ f16 act1[2048];        // 16 rows x 128 cols (h1)
  __shared__ f16 act2[2048];        // 16 rows x 128 cols (h2)
  __shared__ f16 lds_ld[32 * 144];  // 32 rows x 144 chol cols (136 real)

  const int lane = threadIdx.x & 63;
  const int w = threadIdx.x >> 6;  // wave 0..3
  const int cl = lane & 15;        // A-row / C-col index
  const int q = lane >> 4;         // quad: k-chunk / C-row-group
  const f16* w1t = wt;             // [128][64]
  const f16* w2t = wt + 8192;      // [128][128]
  const f16* w3t = wt + 24576;     // [144][128]

  // ---- one-time: this wave's quarter of W1/W2/W3 fragments + biases ----
  half8_t w1f[2][2], w2f[2][4], w3f[3][4];
  float bias1[2], bias2[2], bias3[3];
#pragma unroll
  for (int j = 0; j < 2; ++j) {
    int c8g = w + 4 * j;
    int c = c8g * 16 + cl;
#pragma unroll
    for (int ks = 0; ks < 2; ++ks)
      w1f[j][ks] = *(const half8_t*)(w1t + c * 64 + ks * 32 + q * 8);
#pragma unroll
    for (int ks = 0; ks < 4; ++ks)
      w2f[j][ks] = *(const half8_t*)(w2t + c * 128 + ks * 32 + q * 8);
    bias1[j] = b1[c];
    bias2[j] = b2v[c];
  }
#pragma unroll
  for (int j = 0; j < 3; ++j) {
    int c8g = w + 4 * j;
    int c8c = c8g < 9 ? c8g : 8;  // clamp so loads stay in-bounds (unused)
    int c = c8c * 16 + cl;
#pragma unroll
    for (int ks = 0; ks < 4; ++ks)
      w3f[j][ks] = *(const half8_t*)(w3t + c * 128 + ks * 32 + q * 8);
    int cc = c8g * 16 + cl;
    bias3[j] = (cc < 136) ? b3[cc] : 0.f;
  }

  const int r0b = blockIdx.x * 32;
  // prefetch row-tile 0's x rows (all 4 waves load same addrs: L1-hit)
  const float* xp = x + (size_t)(r0b + cl) * 64 + q * 8;
  floatx4 v0 = *(const floatx4*)xp;
  floatx4 v1 = *(const floatx4*)(xp + 4);
  floatx4 v2 = *(const floatx4*)(xp + 32);
  floatx4 v3 = *(const floatx4*)(xp + 36);

  for (int t = 0; t < 2; ++t) {
    half8_t a0, a1;
#pragma unroll
    for (int i = 0; i < 4; ++i) {
      a0[i] = (f16)v0[i]; a0[i + 4] = (f16)v1[i];
      a1[i] = (f16)v2[i]; a1[i + 4] = (f16)v3[i];
    }
    if (t == 0) {  // prefetch tile 1's x rows
      xp = x + (size_t)(r0b + 16 + cl) * 64 + q * 8;
      v0 = *(const floatx4*)xp;
      v1 = *(const floatx4*)(xp + 4);
      v2 = *(const floatx4*)(xp + 32);
      v3 = *(const floatx4*)(xp + 36);
    }

    // ---- Layer 1: [16x64] @ [64x128], this wave's 2 col-groups ----
#pragma unroll
    for (int j = 0; j < 2; ++j) {
      int c8g = w + 4 * j;
      floatx4 acc = {0.f, 0.f, 0.f, 0.f};
      acc = __builtin_amdgcn_mfma_f32_16x16x32_f16(a0, w1f[j][0], acc, 0, 0, 0);
      acc = __builtin_amdgcn_mfma_f32_16x16x32_f16(a1, w1f[j][1], acc, 0, 0, 0);
#pragma unroll
      for (int i = 0; i < 4; ++i) {
        float v = acc[i] + bias1[j];
        v = v > 0.f ? v : 0.01f * v;  // LeakyReLU
        int row = q * 4 + i;
        int gs = ((c8g * 2 + (cl >> 3)) ^ row) & 15;  // XOR-swizzled group
        act1[row * 128 + gs * 8 + (cl & 7)] = (f16)v;
      }
    }
    __syncthreads();

    half8_t ha[4];
#pragma unroll
    for (int ks = 0; ks < 4; ++ks)
      ha[ks] = *(const half8_t*)(act1 + cl * 128 +
                                 ((((ks << 2) | q) ^ cl) << 3));

    // ---- Layer 2: [16x128] @ [128x128] ----
#pragma unroll
    for (int j = 0; j < 2; ++j) {
      int c8g = w + 4 * j;
      floatx4 acc = {0.f, 0.f, 0.f, 0.f};
#pragma unroll
      for (int ks = 0; ks < 4; ++ks)
        acc = __builtin_amdgcn_mfma_f32_16x16x32_f16(ha[ks], w2f[j][ks], acc,
                                                     0, 0, 0);
#pragma unroll
      for (int i = 0; i < 4; ++i) {
        float v = acc[i] + bias2[j];
        v = v > 0.f ? v : 0.01f * v;
        int row = q * 4 + i;
        int gs = ((c8g * 2 + (cl >> 3)) ^ row) & 15;
        act2[row * 128 + gs * 8 + (cl & 7)] = (f16)v;
      }
    }
    __syncthreads();

#pragma unroll
    for (int ks = 0; ks < 4; ++ks)
      ha[ks] = *(const half8_t*)(act2 + cl * 128 +
                                 ((((ks << 2) | q) ^ cl) << 3));

    // ---- Layer 3: [16x128] @ [128x136] + tanh -> ldata in LDS ----
#pragma unroll
    for (int j = 0; j < 3; ++j) {
      int c8g = w + 4 * j;
      if (c8g < 9) {
        floatx4 acc = {0.f, 0.f, 0.f, 0.f};
#pragma unroll
        for (int ks = 0; ks < 4; ++ks)
          acc = __builtin_amdgcn_mfma_f32_16x16x32_f16(ha[ks], w3f[j][ks], acc,
                                                       0, 0, 0);
        int c = c8g * 16 + cl;  // 0..143; cols >=136 are zero-weight scratch
#pragma unroll
        for (int i = 0; i < 4; ++i) {
          float v = fast_tanh(acc[i] + bias3[j]);
          lds_ld[(t * 16 + q * 4 + i) * 144 + c] = (f16)v;
        }
      }
    }
    // no barrier here: next tile touches act1 only after its own post-L1
    // barrier, and all act1/act2 reads for this tile already happened.
  }
  __syncthreads();  // ldata complete in LDS

  // ---- expm phase: 8 matrices per wave as 4 interleaved PAIRS ----
  const int r = cl;
  floatx4 I4;
#pragma unroll
  for (int i = 0; i < 4; ++i) I4[i] = (r == q * 4 + i) ? 1.f : 0.f;

  for (int pp = 0; pp < 4; ++pp) {
    const int mA_loc = w * 8 + pp * 2;
    const int mB_loc = mA_loc + 1;
    const f16* ldA = lds_ld + mA_loc * 144;
    const f16* ldB = lds_ld + mB_loc * 144;

    floatx4 bA, bB;
#pragma unroll
    for (int i = 0; i < 4; ++i) {
      int k = q * 4 + i;
      int hi = r > k ? r : k;
      int lo = r + k - hi;
      int idx = hi * (hi + 1) / 2 + lo;  // tril row-major index
      float vA = (float)ldA[idx];
      float vB = (float)ldB[idx];
      bool d = (r == k);
      bA[i] = d ? 4.f * vA : 2.f * vA;  // b = 2*Q (Q diag = 2*ldata)
      bB[i] = d ? 4.f * vB : 2.f * vB;
    }

    // expm #1: p = expm(2Q - m1 I);  Z/2 = e^{m1}/2 * p (exact algebra)
    float m1A, m1B;
    floatx4 pA, pB;
    expm_c2(pA, pB, bA, bB, I4, m1A, m1B);
    float facA = __builtin_amdgcn_exp2f(m1A * 1.4426950408889634f - 1.0f);
    float facB = __builtin_amdgcn_exp2f(m1B * 1.4426950408889634f - 1.0f);
    // expm #2: shift constant cancels in the final Frobenius normalization
    float m2A, m2B;
    expm_c2(pA, pB, pA * facA, pB * facB, I4, m2A, m2B);

    float n2A = wsum(dot4(pA, pA));
    float n2B = wsum(dot4(pB, pB));
    floatx4 oA = pA * __builtin_amdgcn_rsqf(n2A);
    floatx4 oB = pB * __builtin_amdgcn_rsqf(n2B);
    // value_i = M[r][4q+i] -> out[mat*256 + r*16 + 4q + i]
    *(floatx4*)(out + (size_t)(r0b + mA_loc) * 256 + r * 16 + q * 4) = oA;
    *(floatx4*)(out + (size_t)(r0b + mB_loc) * 256 + r * 16 + q * 4) = oB;
  }
}

// ------------------------------------------------------------------
extern "C" void kernel_launch(void* const* d_in, const int* in_sizes, int n_in,
                              void* d_out, int out_size, void* d_ws,
                              size_t ws_size, hipStream_t stream) {
  const float* x = (const float*)d_in[0];
  const float* W1 = (const float*)d_in[1];
  const float* b1 = (const float*)d_in[2];
  const float* W2 = (const float*)d_in[3];
  const float* b2 = (const float*)d_in[4];
  const float* W3 = (const float*)d_in[5];
  const float* b3 = (const float*)d_in[6];
  float* out = (float*)d_out;
  f16* wt = (f16*)d_ws;

  prep_weights<<<168, 256, 0, stream>>>(W1, W2, W3, wt);
  fused_kernel<<<2048, 256, 0, stream>>>(x, b1, b2, b3, wt, out);
}